// Round 7
// baseline (243.439 us; speedup 1.0000x reference)
//
#include <hip/hip_runtime.h>

// Multi-threshold spiking neuron scan. x: [T*B, C, H, W] fp32, T=4, K=8.
// Per column: mem += x[t]; spike = largest thre[k]=thresh/2^k with
// mem >= 0.75*thre[k]; out[t] = spike; mem -= spike.
//
// R6 WIN: XCD-segmented sweep (block b -> segment b%8) broke the 88us wall;
// kernel now < 79us (dropped out of rocprof top-5; harness fills at ~80us
// prove 6.7 TB/s is attainable). R7: single-variable change on R6 —
// double per-wave per-stream burst: each block covers CHUNK=512 contiguous
// float4 columns (2 adjacent coalesced chunks/thread), so each of the 8
// read/write streams presents 8 KB contiguous per wave instead of 4 KB.

constexpr int T_STEPS = 4;
constexpr int BLOCK = 256;
constexpr int NXCD = 8;
constexpr int COLS = 2;                    // adjacent wave-chunks per block
constexpr int CHUNK = COLS * BLOCK;        // 512 float4 columns per block

typedef float v4f __attribute__((ext_vector_type(4)));

// Exact spike via fp32 bit ordering (thresh > 0 normal, mem non-NaN):
// positive fp32 compare == int compare of bits; thr75[k] bits = b75_0 - k*2^23;
// k* = max(0, ceil((b75_0 - bits(mem)) / 2^23)); spike bits = bth0 - k*2^23;
// mem < thr75[7] (incl. mem<=0 via signed cmp) -> 0. Verified absmax=0 (R5/R6).
__device__ __forceinline__ float spike_of(float mem, int b75_0, int b75_7, int bth0) {
    int u = __float_as_int(mem);
    int d = (int)((unsigned)b75_0 - (unsigned)u);
    int k = (int)((unsigned)d + 0x7fffffu) >> 23;
    k = k > 0 ? k : 0;
    int sb = bth0 - (k << 23);
    return (u >= b75_7) ? __int_as_float(sb) : 0.0f;
}

__device__ __forceinline__ void run_chain(const v4f xc[T_STEPS], v4f sp[T_STEPS],
                                          int b75_0, int b75_7, int bth0) {
#pragma unroll
    for (int e = 0; e < 4; ++e) {
        float mem = xc[0][e];
        float s0 = spike_of(mem, b75_0, b75_7, bth0);
        sp[0][e] = s0;
        mem = mem - s0 + xc[1][e];
        float s1 = spike_of(mem, b75_0, b75_7, bth0);
        sp[1][e] = s1;
        mem = mem - s1 + xc[2][e];
        float s2 = spike_of(mem, b75_0, b75_7, bth0);
        sp[2][e] = s2;
        mem = mem - s2 + xc[3][e];
        sp[3][e] = spike_of(mem, b75_0, b75_7, bth0);
    }
}

__global__ __launch_bounds__(BLOCK) void snn_mth_kernel(
    const float* __restrict__ x,
    const float* __restrict__ p_thresh,
    float* __restrict__ out,
    int s4)   // float4 columns per timestep
{
    const float thresh = *p_thresh;
    const int bth0  = __float_as_int(thresh);
    const int b75_0 = __float_as_int(0.75f * thresh);
    const int b75_7 = b75_0 - 7 * 0x800000;

    const v4f* __restrict__ xv = reinterpret_cast<const v4f*>(x);
    v4f* __restrict__ ov = reinterpret_cast<v4f*>(out);
    const size_t n = (size_t)s4;

    // XCD-segmented mapping (validated R6): segment = b % NXCD matches the
    // CP's round-robin block->XCD dispatch; slot = b / NXCD sweeps within
    // the segment so each XCD's L2 works a contiguous 1/8 of j-space.
    const int seg_cols    = s4 / (NXCD * CHUNK) * CHUNK;   // per-segment, CHUNK-aligned
    const int seg_blocks  = seg_cols / CHUNK;
    const int main_blocks = seg_blocks * NXCD;

    const int b = blockIdx.x;
    if (b < main_blocks) {
        const int xcd  = b % NXCD;
        const int slot = b / NXCD;
        const size_t cb = (size_t)xcd * seg_cols + (size_t)slot * CHUNK;

        size_t j[COLS];
#pragma unroll
        for (int c = 0; c < COLS; ++c) j[c] = cb + (size_t)c * BLOCK + threadIdx.x;

        v4f xc[COLS][T_STEPS];
        // All 8 loads issued back-to-back: per stream t, the wave covers
        // 8 KB contiguous (two adjacent coalesced 4 KB chunks).
#pragma unroll
        for (int t = 0; t < T_STEPS; ++t)
#pragma unroll
            for (int c = 0; c < COLS; ++c)
                xc[c][t] = xv[(size_t)t * n + j[c]];

        v4f sp[COLS][T_STEPS];
#pragma unroll
        for (int c = 0; c < COLS; ++c)
            run_chain(xc[c], sp[c], b75_0, b75_7, bth0);

#pragma unroll
        for (int t = 0; t < T_STEPS; ++t)
#pragma unroll
            for (int c = 0; c < COLS; ++c)
                __builtin_nontemporal_store(sp[c][t], &ov[(size_t)t * n + j[c]]);
    } else {
        // Tail: columns not covered by the segmented main region
        // (empty for the benchmark shape; s4 = 2^21 divides evenly).
        const size_t tail0 = (size_t)NXCD * seg_cols;
        const size_t base = tail0 + (size_t)(b - main_blocks) * CHUNK;
#pragma unroll
        for (int c = 0; c < COLS; ++c) {
            const size_t j = base + (size_t)c * BLOCK + threadIdx.x;
            if (j >= n) continue;
            v4f xc[T_STEPS], sp[T_STEPS];
#pragma unroll
            for (int t = 0; t < T_STEPS; ++t) xc[t] = xv[(size_t)t * n + j];
            run_chain(xc, sp, b75_0, b75_7, bth0);
#pragma unroll
            for (int t = 0; t < T_STEPS; ++t)
                __builtin_nontemporal_store(sp[t], &ov[(size_t)t * n + j]);
        }
    }
}

extern "C" void kernel_launch(void* const* d_in, const int* in_sizes, int n_in,
                              void* d_out, int out_size, void* d_ws, size_t ws_size,
                              hipStream_t stream) {
    const float* x = (const float*)d_in[0];
    const float* p_thresh = (const float*)d_in[1];
    float* out = (float*)d_out;

    const int total = in_sizes[0];          // T*B*C*H*W
    const int S = total / T_STEPS;          // spatial elements per timestep
    const int s4 = S >> 2;                  // float4 columns

    const int seg_cols    = s4 / (NXCD * CHUNK) * CHUNK;
    const int main_blocks = (seg_cols / CHUNK) * NXCD;
    const int tail_cols   = s4 - NXCD * seg_cols;
    const int tail_blocks = (tail_cols + CHUNK - 1) / CHUNK;

    snn_mth_kernel<<<main_blocks + tail_blocks, BLOCK, 0, stream>>>(
        x, p_thresh, out, s4);
}

// Round 8
// 235.944 us; speedup vs baseline: 1.0318x; 1.0318x over previous
//
#include <hip/hip_runtime.h>

// Multi-threshold spiking neuron scan. x: [T*B, C, H, W] fp32, T=4, K=8.
// Per column: mem += x[t]; spike = largest thre[k]=thresh/2^k with
// mem >= 0.75*thre[k]; out[t] = spike; mem -= spike.
//
// History: R1-R5 ~88us (2.3 TB/s) regardless of per-thread MLP / VALU count.
// R6 WIN: XCD-segmented sweep (block b -> XCD b%8, contiguous 1/8 of space
// per XCD) -> kernel <79us. R7 FAILED: COLS=2 burst -> 86us (compiler
// serialized; grid halved). R8: R6 segmentation + R5 persistent depth-2
// pipeline -> every CU keeps loads (next set) AND stores (prev set) in
// flight continuously within its XCD-local window; no launch churn.

constexpr int T_STEPS = 4;
constexpr int BLOCK = 256;
constexpr int NXCD = 8;
constexpr int GRID = 2048;                  // 8 blocks/CU, 100% wave occupancy
constexpr int BPX = GRID / NXCD;            // blocks per XCD

typedef float v4f __attribute__((ext_vector_type(4)));

// Exact spike via fp32 bit ordering (thresh > 0 normal, mem non-NaN):
// positive fp32 compare == int compare of bits; thr75[k] bits = b75_0 - k*2^23;
// k* = max(0, ceil((b75_0 - bits(mem)) / 2^23)); spike bits = bth0 - k*2^23;
// mem < thr75[7] (incl. mem<=0 via signed cmp) -> 0. absmax=0 verified R5-R7.
__device__ __forceinline__ float spike_of(float mem, int b75_0, int b75_7, int bth0) {
    int u = __float_as_int(mem);
    int d = (int)((unsigned)b75_0 - (unsigned)u);
    int k = (int)((unsigned)d + 0x7fffffu) >> 23;
    k = k > 0 ? k : 0;
    int sb = bth0 - (k << 23);
    return (u >= b75_7) ? __int_as_float(sb) : 0.0f;
}

__device__ __forceinline__ void load4(v4f dst[T_STEPS], const v4f* __restrict__ xv,
                                      size_t n, size_t j) {
#pragma unroll
    for (int t = 0; t < T_STEPS; ++t) dst[t] = xv[(size_t)t * n + j];
}

__device__ __forceinline__ void process_store(const v4f a[T_STEPS],
                                              v4f* __restrict__ ov,
                                              size_t n, size_t j,
                                              int b75_0, int b75_7, int bth0) {
    v4f sp[T_STEPS];
#pragma unroll
    for (int e = 0; e < 4; ++e) {
        float mem = a[0][e];
        float s0 = spike_of(mem, b75_0, b75_7, bth0);
        sp[0][e] = s0;
        mem = mem - s0 + a[1][e];
        float s1 = spike_of(mem, b75_0, b75_7, bth0);
        sp[1][e] = s1;
        mem = mem - s1 + a[2][e];
        float s2 = spike_of(mem, b75_0, b75_7, bth0);
        sp[2][e] = s2;
        mem = mem - s2 + a[3][e];
        sp[3][e] = spike_of(mem, b75_0, b75_7, bth0);
    }
#pragma unroll
    for (int t = 0; t < T_STEPS; ++t)
        __builtin_nontemporal_store(sp[t], &ov[(size_t)t * n + j]);
}

__global__ __launch_bounds__(BLOCK) void snn_mth_kernel(
    const float* __restrict__ x,
    const float* __restrict__ p_thresh,
    float* __restrict__ out,
    int s4)   // float4 columns per timestep
{
    const float thresh = *p_thresh;
    const int bth0  = __float_as_int(thresh);
    const int b75_0 = __float_as_int(0.75f * thresh);
    const int b75_7 = b75_0 - 7 * 0x800000;

    const v4f* __restrict__ xv = reinterpret_cast<const v4f*>(x);
    v4f* __restrict__ ov = reinterpret_cast<v4f*>(out);
    const size_t n = (size_t)s4;

    // XCD-segmented persistent sweep: block b -> XCD b%8 (CP round-robin);
    // the 256 blocks of one XCD stride through that XCD's contiguous 1/8
    // of j-space, depth-2 pipelined (prefetch set i+1 while computing i).
    const size_t seg_cols = ((size_t)s4 + NXCD - 1) / NXCD;
    const int xcd  = blockIdx.x % NXCD;
    const int slot = blockIdx.x / NXCD;
    const size_t seg_lo  = (size_t)xcd * seg_cols;
    const size_t seg_hi  = seg_lo + seg_cols < n ? seg_lo + seg_cols : n;
    const size_t stride  = (size_t)BPX * BLOCK;

    v4f A[T_STEPS], B[T_STEPS];
    size_t jA = seg_lo + (size_t)slot * BLOCK + threadIdx.x;
    bool actA = jA < seg_hi;
    if (actA) load4(A, xv, n, jA);

    while (actA) {
        const size_t jB = jA + stride;
        const bool actB = jB < seg_hi;
        if (actB) load4(B, xv, n, jB);                 // prefetch next set
        process_store(A, ov, n, jA, b75_0, b75_7, bth0);

        const size_t jN = jB + stride;
        actA = jN < seg_hi;
        if (actA) load4(A, xv, n, jN);                 // prefetch next set
        if (!actB) break;
        process_store(B, ov, n, jB, b75_0, b75_7, bth0);
        jA = jN;
    }
}

extern "C" void kernel_launch(void* const* d_in, const int* in_sizes, int n_in,
                              void* d_out, int out_size, void* d_ws, size_t ws_size,
                              hipStream_t stream) {
    const float* x = (const float*)d_in[0];
    const float* p_thresh = (const float*)d_in[1];
    float* out = (float*)d_out;

    const int total = in_sizes[0];          // T*B*C*H*W
    const int S = total / T_STEPS;          // spatial elements per timestep
    const int s4 = S >> 2;                  // float4 columns

    snn_mth_kernel<<<GRID, BLOCK, 0, stream>>>(x, p_thresh, out, s4);
}